// Round 9
// baseline (4887.321 us; speedup 1.0000x reference)
//
#include <hip/hip_runtime.h>
#include <math.h>

#define VOCAB 1000
#define EMB   128
#define HID   256
#define G4    1024   // 4*HID
#define BATCH 64
#define SEQT  1024
#define KV    96     // half2 k-columns held in VGPRs (k in [0,192))
#define KL    32     // half2 k-columns held in LDS   (k in [192,256))

typedef unsigned int u32;
typedef _Float16 f16;
typedef __attribute__((ext_vector_type(2))) _Float16 h2v;
union H2U { u32 u; h2v h; unsigned short s[2]; };

#if defined(__has_builtin)
# if __has_builtin(__builtin_amdgcn_fdot2)
#  define HAVE_FDOT2 1
# endif
#endif
__device__ __forceinline__ float fdot2_(h2v a, h2v b, float c) {
#ifdef HAVE_FDOT2
    return __builtin_amdgcn_fdot2(a, b, c, false);   // v_dot2_f32_f16
#else
    return c + (float)a.x * (float)b.x + (float)a.y * (float)b.y;
#endif
}

__device__ __forceinline__ float sigmoidf_(float x) {
    return 1.f / (1.f + __expf(-x));
}
__device__ __forceinline__ float tanhf_(float x) {
    return 1.f - 2.f / (__expf(2.f * x) + 1.f);
}

// ---------------------------------------------------------------------------
// Kernel 1: eproj[v][g] = emb[v] . W_ih[g] + b_ih[g] + b_hh[g]   (fp32, exact)
// ---------------------------------------------------------------------------
__global__ __launch_bounds__(1024) void eproj_kernel(
    const float* __restrict__ emb, const float* __restrict__ W_ih,
    const float* __restrict__ b_ih, const float* __restrict__ b_hh,
    float* __restrict__ eproj)
{
    const int v = blockIdx.x;
    const int g = threadIdx.x;
    __shared__ __align__(16) float x_sh[EMB];
    if (g < EMB / 4) {
        ((float4*)x_sh)[g] = ((const float4*)(emb + (size_t)v * EMB))[g];
    }
    __syncthreads();
    const float4* wrow = (const float4*)(W_ih + (size_t)g * EMB);
    float a0 = 0.f, a1 = 0.f, a2 = 0.f, a3 = 0.f;
#pragma unroll
    for (int e4 = 0; e4 < EMB / 4; e4++) {
        float4 wv = wrow[e4];
        float4 xv = ((const float4*)x_sh)[e4];
        a0 += wv.x * xv.x;
        a1 += wv.y * xv.y;
        a2 += wv.z * xv.z;
        a3 += wv.w * xv.w;
    }
    eproj[(size_t)v * G4 + g] = (a0 + a1) + (a2 + a3) + b_ih[g] + b_hh[g];
}

// ---------------------------------------------------------------------------
// Kernel 2: pack W_hh fp32 -> fp16 half2, split into VGPR part [row][96] and
// LDS part transposed [m][row] (m = half2 col 0..31 covering k in [192,256)).
// ---------------------------------------------------------------------------
__global__ __launch_bounds__(128) void pack_whh(
    const float* __restrict__ Whh, u32* __restrict__ wv, u32* __restrict__ wl)
{
    const int row = blockIdx.x;      // 0..1023
    const int m   = threadIdx.x;     // 0..127 (half2 col)
    H2U u;
    u.h.x = (f16)Whh[(size_t)row * HID + 2 * m];
    u.h.y = (f16)Whh[(size_t)row * HID + 2 * m + 1];
    if (m < KV) wv[(size_t)row * KV + m] = u.u;
    else        wl[(size_t)(m - KV) * G4 + row] = u.u;
}

// ---------------------------------------------------------------------------
// Kernel 3: single-CU LSTM. One block (256 thr, 4 waves, 1 wave/SIMD ->
// 512-reg unified budget) per batch element. Thread j owns ALL FOUR gate
// rows of hidden unit j: 4x96 half2 in registers + 4x32 half2 streamed from
// LDS (conflict-free transposed layout). All gates local => no gate
// exchange, c in a register, ONE barrier per step, ZERO cross-CU traffic.
// h recurrence in fp16 (dot2), c/out in fp32.
// ---------------------------------------------------------------------------
__global__ __launch_bounds__(256, 1) void lstm_single_cu(
    const int* __restrict__ ids, const int* __restrict__ lens,
    const float* __restrict__ eproj,
    const u32* __restrict__ wv, const u32* __restrict__ wl,
    float* __restrict__ out)
{
    const int b = blockIdx.x;
    const int j = threadIdx.x;                   // hidden unit 0..255
    const int r0 = j, r1 = HID + j, r2 = 2 * HID + j, r3 = 3 * HID + j;

    __shared__ u32 wl_sh[KL * G4];               // 128 KB weight tail
    __shared__ u32 h2_sh[2][HID / 2];            // h as half2, parity x2

    // stage LDS weight tail (coalesced, 128 u32/thread, one-time)
#pragma unroll 8
    for (int t = 0; t < (KL * G4) / 256; t++)
        wl_sh[t * 256 + j] = wl[t * 256 + j];
    if (j < HID / 2) h2_sh[0][j] = 0u;           // h(0) = 0

    // VGPR weights: 4 rows x 96 half2 = 384 regs (unified VGPR/AGPR file)
    u32 w0[KV], w1[KV], w2[KV], w3[KV];
#pragma unroll
    for (int q = 0; q < KV / 4; q++) {
        ((uint4*)w0)[q] = ((const uint4*)(wv + (size_t)r0 * KV))[q];
        ((uint4*)w1)[q] = ((const uint4*)(wv + (size_t)r1 * KV))[q];
        ((uint4*)w2)[q] = ((const uint4*)(wv + (size_t)r2 * KV))[q];
        ((uint4*)w3)[q] = ((const uint4*)(wv + (size_t)r3 * KV))[q];
    }

    const int len = lens[b];                     // >= 1
    const int* idr = ids + (size_t)b * SEQT;
    float c = 0.f, hf = 0.f;

    const float* e0 = eproj + (size_t)idr[0] * G4;
    float x0 = e0[r0], x1 = e0[r1], x2 = e0[r2], x3 = e0[r3];

    __syncthreads();

    for (int t = 0; t < len; t++) {
        // prefetch next step's input projections (hidden under k-loop)
        const int nt = (t + 1 < len) ? t + 1 : len - 1;
        const float* en = eproj + (size_t)idr[nt] * G4;
        const float n0 = en[r0], n1 = en[r1], n2 = en[r2], n3 = en[r3];

        const u32* hb = h2_sh[t & 1];
        float a0 = x0, a1 = x1, a2 = x2, a3 = x3;
#pragma unroll
        for (int m = 0; m < KV; m++) {
            H2U h; h.u = hb[m];                  // broadcast (conflict-free)
            H2U q0, q1, q2, q3;
            q0.u = w0[m]; q1.u = w1[m]; q2.u = w2[m]; q3.u = w3[m];
            a0 = fdot2_(q0.h, h.h, a0);
            a1 = fdot2_(q1.h, h.h, a1);
            a2 = fdot2_(q2.h, h.h, a2);
            a3 = fdot2_(q3.h, h.h, a3);
        }
#pragma unroll
        for (int m = 0; m < KL; m++) {
            H2U h; h.u = hb[KV + m];
            H2U q0, q1, q2, q3;                  // lane stride 4B: no conflicts
            q0.u = wl_sh[m * G4 + r0];
            q1.u = wl_sh[m * G4 + r1];
            q2.u = wl_sh[m * G4 + r2];
            q3.u = wl_sh[m * G4 + r3];
            a0 = fdot2_(q0.h, h.h, a0);
            a1 = fdot2_(q1.h, h.h, a1);
            a2 = fdot2_(q2.h, h.h, a2);
            a3 = fdot2_(q3.h, h.h, a3);
        }

        // activation: fully thread-local (i,f,g,o all owned by this thread)
        float ig = sigmoidf_(a0);
        float fg = sigmoidf_(a1);
        float gg = tanhf_(a2);
        float og = sigmoidf_(a3);
        c = fg * c + ig * gg;
        hf = og * tanhf_(c);

        // publish h (fp16) into the other parity buffer; safe with a single
        // barrier because step t never reads buffer (t+1)&1
        H2U hv16; hv16.h.x = (f16)hf; hv16.h.y = (f16)0.f;
        ((unsigned short*)h2_sh[(t + 1) & 1])[j] = hv16.s[0];

        x0 = n0; x1 = n1; x2 = n2; x3 = n3;
        __syncthreads();                         // the ONE barrier per step
    }

    out[(size_t)b * HID + j] = hf;               // fp32 state of own unit
}

// ---------------------------------------------------------------------------
// Fallback (ws too small): correct-but-slow single-block fp32 version.
// ---------------------------------------------------------------------------
__global__ __launch_bounds__(1024, 1) void lstm_fallback(
    const int* __restrict__ ids, const int* __restrict__ lens,
    const float* __restrict__ emb, const float* __restrict__ W_ih,
    const float* __restrict__ b_ih, const float* __restrict__ b_hh,
    const float* __restrict__ W_hh, float* __restrict__ out)
{
    const int b = blockIdx.x;
    const int t = threadIdx.x;

    __shared__ __align__(16) float h_sh[HID];
    __shared__ __align__(16) float c_sh[HID];
    __shared__ __align__(16) float gates[G4];
    __shared__ __align__(16) float x_sh[EMB];

    float wih[EMB];
    {
        const float4* wr = (const float4*)(W_ih + (size_t)t * EMB);
#pragma unroll
        for (int e4 = 0; e4 < EMB / 4; e4++) {
            float4 wv = wr[e4];
            wih[4 * e4 + 0] = wv.x;
            wih[4 * e4 + 1] = wv.y;
            wih[4 * e4 + 2] = wv.z;
            wih[4 * e4 + 3] = wv.w;
        }
    }
    float bias = b_ih[t] + b_hh[t];

    const int len = lens[b];
    const int* ids_row = ids + (size_t)b * SEQT;
    if (t < HID) { h_sh[t] = 0.f; c_sh[t] = 0.f; }
    __syncthreads();

    for (int step = 0; step < len; step++) {
        int id = ids_row[step];
        if (t < EMB / 4) {
            ((float4*)x_sh)[t] = ((const float4*)(emb + (size_t)id * EMB))[t];
        }
        __syncthreads();
        float a0 = bias, a1 = 0.f, a2 = 0.f, a3 = 0.f;
#pragma unroll
        for (int e4 = 0; e4 < EMB / 4; e4++) {
            float4 xv = ((const float4*)x_sh)[e4];
            a0 += wih[4 * e4 + 0] * xv.x;
            a1 += wih[4 * e4 + 1] * xv.y;
            a2 += wih[4 * e4 + 2] * xv.z;
            a3 += wih[4 * e4 + 3] * xv.w;
        }
        float acc = (a0 + a1) + (a2 + a3);

        const float* wrow = W_hh + (size_t)t * HID;
        a0 = acc; a1 = 0.f; a2 = 0.f; a3 = 0.f;
        for (int k4 = 0; k4 < HID / 4; k4++) {
            float4 hv = ((const float4*)h_sh)[k4];
            float4 wv = ((const float4*)wrow)[k4];
            a0 += wv.x * hv.x;
            a1 += wv.y * hv.y;
            a2 += wv.z * hv.z;
            a3 += wv.w * hv.w;
        }
        gates[t] = (a0 + a1) + (a2 + a3);
        __syncthreads();

        if (t < HID) {
            float ig = sigmoidf_(gates[t]);
            float fg = sigmoidf_(gates[HID + t]);
            float gg = tanhf_(gates[2 * HID + t]);
            float og = sigmoidf_(gates[3 * HID + t]);
            float cc = fg * c_sh[t] + ig * gg;
            c_sh[t] = cc;
            h_sh[t] = og * tanhf_(cc);
        }
        __syncthreads();
    }
    if (t < HID) out[(size_t)b * HID + t] = h_sh[t];
}

extern "C" void kernel_launch(void* const* d_in, const int* in_sizes, int n_in,
                              void* d_out, int out_size, void* d_ws, size_t ws_size,
                              hipStream_t stream) {
    const int*   ids  = (const int*)d_in[0];
    const int*   lens = (const int*)d_in[1];
    const float* emb  = (const float*)d_in[2];
    const float* Wih  = (const float*)d_in[3];
    const float* Whh  = (const float*)d_in[4];
    const float* bih  = (const float*)d_in[5];
    const float* bhh  = (const float*)d_in[6];
    float* out = (float*)d_out;

    // ws layout: eproj 4 MB | wv 384 KB | wl 128 KB
    const size_t ep_bytes = (size_t)VOCAB * G4 * sizeof(float);
    const size_t wv_off   = ep_bytes;
    const size_t wv_bytes = (size_t)G4 * KV * sizeof(u32);
    const size_t wl_off   = wv_off + wv_bytes;
    const size_t wl_bytes = (size_t)KL * G4 * sizeof(u32);

    if (ws_size >= wl_off + wl_bytes) {
        float* eproj = (float*)d_ws;
        u32*   wvp   = (u32*)((char*)d_ws + wv_off);
        u32*   wlp   = (u32*)((char*)d_ws + wl_off);
        eproj_kernel<<<VOCAB, 1024, 0, stream>>>(emb, Wih, bih, bhh, eproj);
        pack_whh<<<G4, 128, 0, stream>>>(Whh, wvp, wlp);
        lstm_single_cu<<<BATCH, 256, 0, stream>>>(ids, lens, eproj, wvp, wlp, out);
    } else {
        lstm_fallback<<<BATCH, 1024, 0, stream>>>(
            ids, lens, emb, Wih, bih, bhh, Whh, out);
    }
}

// Round 10
// 1765.984 us; speedup vs baseline: 2.7675x; 2.7675x over previous
//
#include <hip/hip_runtime.h>
#include <math.h>

#define VOCAB 1000
#define EMB   128
#define HID   256
#define G4    1024   // 4*HID
#define BATCH 64
#define SEQT  1024
#define KV    92     // half2 cols in VGPRs  (k in [0,184))
#define KL    36     // half2 cols in LDS    (k in [184,256)), 9 b128 chunks

typedef unsigned int u32;
typedef _Float16 f16;
typedef __attribute__((ext_vector_type(2))) _Float16 h2v;
union H2U { u32 u; h2v h; unsigned short s[2]; };

#if defined(__has_builtin)
# if __has_builtin(__builtin_amdgcn_fdot2)
#  define HAVE_FDOT2 1
# endif
#endif
__device__ __forceinline__ float fdot2_(u32 a, u32 b, float c) {
    H2U ua, ub; ua.u = a; ub.u = b;
#ifdef HAVE_FDOT2
    return __builtin_amdgcn_fdot2(ua.h, ub.h, c, false);   // v_dot2_f32_f16
#else
    return c + (float)ua.h.x * (float)ub.h.x + (float)ua.h.y * (float)ub.h.y;
#endif
}

__device__ __forceinline__ float sigmoidf_(float x) {
    return 1.f / (1.f + __expf(-x));
}
__device__ __forceinline__ float tanhf_(float x) {
    return 1.f - 2.f / (__expf(2.f * x) + 1.f);
}

// ---------------------------------------------------------------------------
// Kernel 1: eproj[v][g] = emb[v] . W_ih[g] + b_ih[g] + b_hh[g]   (fp32, exact)
// ---------------------------------------------------------------------------
__global__ __launch_bounds__(1024) void eproj_kernel(
    const float* __restrict__ emb, const float* __restrict__ W_ih,
    const float* __restrict__ b_ih, const float* __restrict__ b_hh,
    float* __restrict__ eproj)
{
    const int v = blockIdx.x;
    const int g = threadIdx.x;
    __shared__ __align__(16) float x_sh[EMB];
    if (g < EMB / 4) {
        ((float4*)x_sh)[g] = ((const float4*)(emb + (size_t)v * EMB))[g];
    }
    __syncthreads();
    const float4* wrow = (const float4*)(W_ih + (size_t)g * EMB);
    float a0 = 0.f, a1 = 0.f, a2 = 0.f, a3 = 0.f;
#pragma unroll
    for (int e4 = 0; e4 < EMB / 4; e4++) {
        float4 wv = wrow[e4];
        float4 xv = ((const float4*)x_sh)[e4];
        a0 += wv.x * xv.x;
        a1 += wv.y * xv.y;
        a2 += wv.z * xv.z;
        a3 += wv.w * xv.w;
    }
    eproj[(size_t)v * G4 + g] = (a0 + a1) + (a2 + a3) + b_ih[g] + b_hh[g];
}

// ---------------------------------------------------------------------------
// Kernel 2: pack W_hh fp32 -> fp16 half2 into two [chunk][row][4] u32 arrays:
// wvq (cols 0..183, 23 chunks) register part, wlq (cols 184..255, 9 chunks)
// LDS part. [chunk][row][4] makes both global loads and LDS b128 reads
// lane-consecutive (canonical conflict-free float4 pattern).
// ---------------------------------------------------------------------------
__global__ __launch_bounds__(128) void pack_whh(
    const float* __restrict__ Whh, u32* __restrict__ wvq, u32* __restrict__ wlq)
{
    const int r = blockIdx.x;        // row 0..1023
    const int m = threadIdx.x;       // half2 col 0..127
    H2U u;
    u.h.x = (f16)Whh[(size_t)r * HID + 2 * m];
    u.h.y = (f16)Whh[(size_t)r * HID + 2 * m + 1];
    if (m < KV) {
        wvq[(size_t)(m >> 2) * (G4 * 4) + r * 4 + (m & 3)] = u.u;
    } else {
        const int mm = m - KV;
        wlq[(size_t)(mm >> 2) * (G4 * 4) + r * 4 + (mm & 3)] = u.u;
    }
}

// ---------------------------------------------------------------------------
// Kernel 3: single-CU LSTM, spill-proof. One block (512 thr, 8 waves,
// 2 waves/SIMD -> hard 256-VGPR cap) per batch element. Thread tau owns gate
// rows tau (i or f) and 512+tau (g or o): 2 x 92 half2 = 184 persistent regs
// (guaranteed fit). Weight tail (36 half2 cols x 1024 rows = 144 KB) in LDS,
// lane-consecutive b128. Unit j's activation: thread j has (i,g), thread
// 256+j passes (f,o) sums through a 2 KB LDS bounce. Zero cross-CU traffic.
// ---------------------------------------------------------------------------
__global__ __launch_bounds__(512, 2) void lstm_single_cu(
    const int* __restrict__ ids, const int* __restrict__ lens,
    const float* __restrict__ eproj,
    const u32* __restrict__ wvq, const u32* __restrict__ wlq,
    float* __restrict__ out)
{
    const int b   = blockIdx.x;
    const int tau = threadIdx.x;                 // 0..511
    const int rA  = tau;                         // gate i (tau<256) / f
    const int rB  = 512 + tau;                   // gate g (tau<256) / o

    __shared__ u32 wl_sh[KL / 4 * G4 * 4];       // 9 chunks x 1024 rows x 16B
    __shared__ u32 h2_sh[2][HID / 2];            // h as half2, parity x2
    __shared__ float gs_f[HID], gs_o[HID];       // f,o gate-sum bounce

    // stage LDS weight tail (b128 both sides, coalesced)
    {
        const uint4* src = (const uint4*)wlq;
        uint4*       dst = (uint4*)wl_sh;
#pragma unroll
        for (int t = 0; t < (KL / 4) * G4 / 512; t++)   // 18 iters
            dst[t * 512 + tau] = src[t * 512 + tau];
    }
    if (tau < HID / 2) h2_sh[0][tau] = 0u;       // h(0) = 0

    // persistent VGPR weights: 2 rows x 92 half2 = 184 regs
    u32 wA[KV], wB[KV];
#pragma unroll
    for (int q = 0; q < KV / 4; q++) {
        uint4 ta = ((const uint4*)wvq)[q * G4 + rA];
        uint4 tb = ((const uint4*)wvq)[q * G4 + rB];
        wA[4 * q + 0] = ta.x; wA[4 * q + 1] = ta.y;
        wA[4 * q + 2] = ta.z; wA[4 * q + 3] = ta.w;
        wB[4 * q + 0] = tb.x; wB[4 * q + 1] = tb.y;
        wB[4 * q + 2] = tb.z; wB[4 * q + 3] = tb.w;
    }

    const int len = lens[b];                     // >= 1
    const int* idr = ids + (size_t)b * SEQT;
    float c = 0.f, hf = 0.f;

    const float* e0 = eproj + (size_t)idr[0] * G4;
    float xA = e0[rA], xB = e0[rB];

    __syncthreads();

    for (int t = 0; t < len; t++) {
        // prefetch next step's input projections (hidden under dot loops)
        const int nt = (t + 1 < len) ? t + 1 : len - 1;
        const float* en = eproj + (size_t)idr[nt] * G4;
        const float nA = en[rA], nB = en[rB];

        const int p = t & 1;
        const uint4* hb4 = (const uint4*)h2_sh[p];   // 32 b128 broadcasts
        float aA = xA, aB = xB;

        // register cols 0..91
#pragma unroll
        for (int q = 0; q < KV / 4; q++) {
            uint4 h4 = hb4[q];
            aA = fdot2_(wA[4 * q + 0], h4.x, aA);
            aB = fdot2_(wB[4 * q + 0], h4.x, aB);
            aA = fdot2_(wA[4 * q + 1], h4.y, aA);
            aB = fdot2_(wB[4 * q + 1], h4.y, aB);
            aA = fdot2_(wA[4 * q + 2], h4.z, aA);
            aB = fdot2_(wB[4 * q + 2], h4.z, aB);
            aA = fdot2_(wA[4 * q + 3], h4.w, aA);
            aB = fdot2_(wB[4 * q + 3], h4.w, aB);
        }
        // LDS tail cols 92..127 (lane-consecutive b128, conflict-free)
#pragma unroll
        for (int q = 0; q < KL / 4; q++) {
            uint4 h4 = hb4[KV / 4 + q];
            uint4 tA = ((const uint4*)wl_sh)[q * G4 + rA];
            uint4 tB = ((const uint4*)wl_sh)[q * G4 + rB];
            aA = fdot2_(tA.x, h4.x, aA);
            aB = fdot2_(tB.x, h4.x, aB);
            aA = fdot2_(tA.y, h4.y, aA);
            aB = fdot2_(tB.y, h4.y, aB);
            aA = fdot2_(tA.z, h4.z, aA);
            aB = fdot2_(tB.z, h4.z, aB);
            aA = fdot2_(tA.w, h4.w, aA);
            aB = fdot2_(tB.w, h4.w, aB);
        }

        if (tau >= HID) {            // rows f,o: pass sums to unit owner
            gs_f[tau - HID] = aA;
            gs_o[tau - HID] = aB;
        }
        __syncthreads();             // barrier A: sums visible

        if (tau < HID) {             // unit owner: i,g local + f,o from LDS
            float ig = sigmoidf_(aA);
            float gg = tanhf_(aB);
            float fg = sigmoidf_(gs_f[tau]);
            float og = sigmoidf_(gs_o[tau]);
            c = fg * c + ig * gg;
            hf = og * tanhf_(c);
            H2U hv; hv.h.x = (f16)hf; hv.h.y = (f16)0.f;
            ((unsigned short*)h2_sh[p ^ 1])[tau] = hv.s[0];
        }
        xA = nA; xB = nB;
        __syncthreads();             // barrier B: h(t+1) published
    }

    if (tau < HID) out[(size_t)b * HID + tau] = hf;
}

// ---------------------------------------------------------------------------
// Fallback (ws too small): correct-but-slow single-block fp32 version.
// ---------------------------------------------------------------------------
__global__ __launch_bounds__(1024, 1) void lstm_fallback(
    const int* __restrict__ ids, const int* __restrict__ lens,
    const float* __restrict__ emb, const float* __restrict__ W_ih,
    const float* __restrict__ b_ih, const float* __restrict__ b_hh,
    const float* __restrict__ W_hh, float* __restrict__ out)
{
    const int b = blockIdx.x;
    const int t = threadIdx.x;

    __shared__ __align__(16) float h_sh[HID];
    __shared__ __align__(16) float c_sh[HID];
    __shared__ __align__(16) float gates[G4];
    __shared__ __align__(16) float x_sh[EMB];

    float wih[EMB];
    {
        const float4* wr = (const float4*)(W_ih + (size_t)t * EMB);
#pragma unroll
        for (int e4 = 0; e4 < EMB / 4; e4++) {
            float4 wv = wr[e4];
            wih[4 * e4 + 0] = wv.x;
            wih[4 * e4 + 1] = wv.y;
            wih[4 * e4 + 2] = wv.z;
            wih[4 * e4 + 3] = wv.w;
        }
    }
    float bias = b_ih[t] + b_hh[t];

    const int len = lens[b];
    const int* ids_row = ids + (size_t)b * SEQT;
    if (t < HID) { h_sh[t] = 0.f; c_sh[t] = 0.f; }
    __syncthreads();

    for (int step = 0; step < len; step++) {
        int id = ids_row[step];
        if (t < EMB / 4) {
            ((float4*)x_sh)[t] = ((const float4*)(emb + (size_t)id * EMB))[t];
        }
        __syncthreads();
        float a0 = bias, a1 = 0.f, a2 = 0.f, a3 = 0.f;
#pragma unroll
        for (int e4 = 0; e4 < EMB / 4; e4++) {
            float4 xv = ((const float4*)x_sh)[e4];
            a0 += wih[4 * e4 + 0] * xv.x;
            a1 += wih[4 * e4 + 1] * xv.y;
            a2 += wih[4 * e4 + 2] * xv.z;
            a3 += wih[4 * e4 + 3] * xv.w;
        }
        float acc = (a0 + a1) + (a2 + a3);

        const float* wrow = W_hh + (size_t)t * HID;
        a0 = acc; a1 = 0.f; a2 = 0.f; a3 = 0.f;
        for (int k4 = 0; k4 < HID / 4; k4++) {
            float4 hv = ((const float4*)h_sh)[k4];
            float4 wv = ((const float4*)wrow)[k4];
            a0 += wv.x * hv.x;
            a1 += wv.y * hv.y;
            a2 += wv.z * hv.z;
            a3 += wv.w * hv.w;
        }
        gates[t] = (a0 + a1) + (a2 + a3);
        __syncthreads();

        if (t < HID) {
            float ig = sigmoidf_(gates[t]);
            float fg = sigmoidf_(gates[HID + t]);
            float gg = tanhf_(gates[2 * HID + t]);
            float og = sigmoidf_(gates[3 * HID + t]);
            float cc = fg * c_sh[t] + ig * gg;
            c_sh[t] = cc;
            h_sh[t] = og * tanhf_(cc);
        }
        __syncthreads();
    }
    if (t < HID) out[(size_t)b * HID + t] = h_sh[t];
}

extern "C" void kernel_launch(void* const* d_in, const int* in_sizes, int n_in,
                              void* d_out, int out_size, void* d_ws, size_t ws_size,
                              hipStream_t stream) {
    const int*   ids  = (const int*)d_in[0];
    const int*   lens = (const int*)d_in[1];
    const float* emb  = (const float*)d_in[2];
    const float* Wih  = (const float*)d_in[3];
    const float* Whh  = (const float*)d_in[4];
    const float* bih  = (const float*)d_in[5];
    const float* bhh  = (const float*)d_in[6];
    float* out = (float*)d_out;

    // ws layout: eproj 4 MB | wvq 368 KB | wlq 144 KB
    const size_t ep_bytes = (size_t)VOCAB * G4 * sizeof(float);
    const size_t wv_off   = ep_bytes;
    const size_t wv_bytes = (size_t)(KV / 4) * G4 * 4 * sizeof(u32);
    const size_t wl_off   = wv_off + wv_bytes;
    const size_t wl_bytes = (size_t)(KL / 4) * G4 * 4 * sizeof(u32);

    if (ws_size >= wl_off + wl_bytes) {
        float* eproj = (float*)d_ws;
        u32*   wvp   = (u32*)((char*)d_ws + wv_off);
        u32*   wlp   = (u32*)((char*)d_ws + wl_off);
        eproj_kernel<<<VOCAB, 1024, 0, stream>>>(emb, Wih, bih, bhh, eproj);
        pack_whh<<<G4, 128, 0, stream>>>(Whh, wvp, wlp);
        lstm_single_cu<<<BATCH, 512, 0, stream>>>(ids, lens, eproj, wvp, wlp, out);
    } else {
        lstm_fallback<<<BATCH, 1024, 0, stream>>>(
            ids, lens, emb, Wih, bih, bhh, Whh, out);
    }
}